// Round 1
// baseline (1710.484 us; speedup 1.0000x reference)
//
#include <hip/hip_runtime.h>
#include <hip/hip_bf16.h>
#include <cstdint>
#include <cstddef>

// Problem constants: B=2048, D=4096, H=2048, L=512, C=10, RLS_INIT=100
// Key math: RLS scan == solve  A W^T = R^T  with
//   A = 0.01*I + z^T z   (all 10 class P's are identical!)
//   R = 0.01*W_out + label^T z
// => prediction = z @ A^{-1} R^T

#define DEV __device__ __forceinline__

typedef __attribute__((ext_vector_type(8))) short bf16x8;
typedef __attribute__((ext_vector_type(4))) float f32x4;

DEV unsigned short f2b(float f) {  // fp32 -> bf16 round-to-nearest-even
  unsigned u = __builtin_bit_cast(unsigned, f);
  u += 0x7FFFu + ((u >> 16) & 1u);
  return (unsigned short)(u >> 16);
}

DEV void load_lds16(void* l, const void* g) {  // async global->LDS, 16B/lane
  __builtin_amdgcn_global_load_lds(
      (const __attribute__((address_space(1))) unsigned int*)g,
      (__attribute__((address_space(3))) unsigned int*)l, 16, 0, 0);
}

// ---------------- fp32 -> bf16 convert (vectorized, exact grid) --------------
__global__ __launch_bounds__(256) void f2bf_k(const float* __restrict__ in,
                                              unsigned short* __restrict__ out) {
  int i = blockIdx.x * 256 + threadIdx.x;
  float4 v = ((const float4*)in)[i];
  ushort4 o;
  o.x = f2b(v.x); o.y = f2b(v.y); o.z = f2b(v.z); o.w = f2b(v.w);
  ((ushort4*)out)[i] = o;
}

// ---------------- bf16 MFMA GEMM: C = act(A[M,K] @ B[N,K]^T + bias) ---------
// 128x128 tile, BK=32, 4 waves (2x2), each wave 64x64 (4x4 frags of 16x16x32).
template<int RELU, int WF32, int WBF16>
__global__ __launch_bounds__(256) void gemm_nt(
    const unsigned short* __restrict__ A, const unsigned short* __restrict__ Bm,
    const float* __restrict__ bias, float* __restrict__ Cf,
    unsigned short* __restrict__ Cb, int N, int K)
{
  __shared__ unsigned short lA[4096];
  __shared__ unsigned short lB[4096];
  const int t = threadIdx.x;
  const int l = t & 63, w = t >> 6;
  const int r0 = blockIdx.y << 7, c0 = blockIdx.x << 7;
  const int srow = (w << 4) + (l >> 2);   // staging row within 64-row chunk
  const int scol = (l & 3) << 3;          // k offset (elems)
  const unsigned short* gA = A + (size_t)(r0 + srow) * K + scol;
  const unsigned short* gB = Bm + (size_t)(c0 + srow) * K + scol;
  unsigned short* dA = lA + (w << 9);     // wave-uniform LDS base
  unsigned short* dB = lB + (w << 9);
  const size_t q1 = (size_t)64 * K;
  f32x4 acc[4][4] = {};
  const int wm = (w >> 1) << 6, wn = (w & 1) << 6;
  const int fr = l & 15;
  const int fk = (l >> 4) << 3;
  for (int k0 = 0; k0 < K; k0 += 32) {
    load_lds16(dA,        gA + k0);
    load_lds16(dA + 2048, gA + k0 + q1);
    load_lds16(dB,        gB + k0);
    load_lds16(dB + 2048, gB + k0 + q1);
    asm volatile("s_waitcnt vmcnt(0)" ::: "memory");
    __syncthreads();
    bf16x8 av[4], bv[4];
#pragma unroll
    for (int mi = 0; mi < 4; ++mi)
      av[mi] = *(const bf16x8*)(lA + ((wm + (mi << 4) + fr) << 5) + fk);
#pragma unroll
    for (int ni = 0; ni < 4; ++ni)
      bv[ni] = *(const bf16x8*)(lB + ((wn + (ni << 4) + fr) << 5) + fk);
#pragma unroll
    for (int mi = 0; mi < 4; ++mi)
#pragma unroll
      for (int ni = 0; ni < 4; ++ni)
        acc[mi][ni] = __builtin_amdgcn_mfma_f32_16x16x32_bf16(av[mi], bv[ni], acc[mi][ni], 0, 0, 0);
    __syncthreads();
  }
  // epilogue: C/D layout col=lane&15, row=(lane>>4)*4+reg  [m89-verified]
#pragma unroll
  for (int mi = 0; mi < 4; ++mi) {
    const int row = r0 + wm + (mi << 4) + ((l >> 4) << 2);
#pragma unroll
    for (int ni = 0; ni < 4; ++ni) {
      const int col = c0 + wn + (ni << 4) + (l & 15);
      const float bvs = bias[col];
#pragma unroll
      for (int r = 0; r < 4; ++r) {
        float v = acc[mi][ni][r] + bvs;
        if (RELU) v = v > 0.f ? v : 0.f;
        const size_t idx = (size_t)(row + r) * N + col;
        if (WF32) Cf[idx] = v;
        if (WBF16) Cb[idx] = f2b(v);
      }
    }
  }
}

// ---------------- z = mu + eps * exp(0.5*logvar) ----------------------------
__global__ __launch_bounds__(256) void z_k(const float* __restrict__ mu,
    const float* __restrict__ lv, const float* __restrict__ eps,
    float* __restrict__ z, unsigned short* __restrict__ zb)
{
  int i = blockIdx.x * 256 + threadIdx.x;
  float4 m = ((const float4*)mu)[i];
  float4 v = ((const float4*)lv)[i];
  float4 e = ((const float4*)eps)[i];
  float4 r;
  r.x = m.x + e.x * expf(0.5f * v.x);
  r.y = m.y + e.y * expf(0.5f * v.y);
  r.z = m.z + e.z * expf(0.5f * v.z);
  r.w = m.w + e.w * expf(0.5f * v.w);
  ((float4*)z)[i] = r;
  ushort4 o; o.x = f2b(r.x); o.y = f2b(r.y); o.z = f2b(r.z); o.w = f2b(r.w);
  ((ushort4*)zb)[i] = o;
}

// ---------------- A = 0.01*I + z^T z  (fp32, 64x64 tiles) -------------------
__global__ __launch_bounds__(256) void gram_k(const float* __restrict__ z,
                                              float* __restrict__ Am)
{
  __shared__ float zi[64 * 65];
  __shared__ float zj[64 * 65];
  const int t = threadIdx.x;
  const int i0 = blockIdx.y << 6, j0 = blockIdx.x << 6;
  const int ti = t >> 4, tj = t & 15;
  float acc[4][4] = {};
  for (int b0 = 0; b0 < 2048; b0 += 64) {
    __syncthreads();
    for (int idx = t; idx < 4096; idx += 256) {
      int r = idx >> 6, c = idx & 63;
      zi[r * 65 + c] = z[(size_t)(b0 + r) * 512 + i0 + c];
      zj[r * 65 + c] = z[(size_t)(b0 + r) * 512 + j0 + c];
    }
    __syncthreads();
    for (int bb = 0; bb < 64; ++bb) {
      float av[4], bv[4];
#pragma unroll
      for (int a = 0; a < 4; ++a) av[a] = zi[bb * 65 + ti * 4 + a];
#pragma unroll
      for (int b = 0; b < 4; ++b) bv[b] = zj[bb * 65 + tj * 4 + b];
#pragma unroll
      for (int a = 0; a < 4; ++a)
#pragma unroll
        for (int b = 0; b < 4; ++b) acc[a][b] += av[a] * bv[b];
    }
  }
#pragma unroll
  for (int a = 0; a < 4; ++a)
#pragma unroll
    for (int b = 0; b < 4; ++b) {
      int gi = i0 + ti * 4 + a, gj = j0 + tj * 4 + b;
      float v = acc[a][b];
      if (gi == gj) v += 0.01f;
      Am[(size_t)gi * 512 + gj] = v;
    }
}

// ---------------- RT[i][c] = sum_b label[b][c] z[b][i] + 0.01*Wout[c][i] ----
__global__ __launch_bounds__(256) void rhs_k(const float* __restrict__ z,
    const float* __restrict__ label, const float* __restrict__ Wout,
    float* __restrict__ RT)
{
  __shared__ float zt[64 * 65];
  __shared__ float lb[640];
  const int t = threadIdx.x;
  const int i0 = blockIdx.x << 6;
  const int w = t >> 6, il = t & 63;
  float a0 = 0.f, a1 = 0.f, a2 = 0.f;
  for (int b0 = 0; b0 < 2048; b0 += 64) {
    __syncthreads();
    for (int idx = t; idx < 4096; idx += 256)
      zt[(idx >> 6) * 65 + (idx & 63)] = z[(size_t)(b0 + (idx >> 6)) * 512 + i0 + (idx & 63)];
    for (int idx = t; idx < 640; idx += 256) lb[idx] = label[b0 * 10 + idx];
    __syncthreads();
    for (int bb = 0; bb < 64; ++bb) {
      float zv = zt[bb * 65 + il];
      a0 += zv * lb[bb * 10 + w];
      a1 += zv * lb[bb * 10 + w + 4];
      if (w < 2) a2 += zv * lb[bb * 10 + w + 8];
    }
  }
  int i = i0 + il;
  RT[i * 10 + w]     = a0 + 0.01f * Wout[w * 512 + i];
  RT[i * 10 + w + 4] = a1 + 0.01f * Wout[(w + 4) * 512 + i];
  if (w < 2) RT[i * 10 + w + 8] = a2 + 0.01f * Wout[(w + 8) * 512 + i];
}

// ---------------- Cholesky panel (64 cols, deferred scaling, rank-4) --------
__global__ __launch_bounds__(512) void chol_panel(float* __restrict__ Am,
                                                  float* __restrict__ LT, int p0)
{
  __shared__ float pan[512 * 65];  // 133 KB
  const int t = threadIdx.x;
  const int h = 512 - p0;
  for (int idx = t; idx < (h << 6); idx += 512) {
    int r = idx >> 6, c = idx & 63;
    pan[r * 65 + c] = Am[(size_t)(p0 + r) * 512 + p0 + c];
  }
  __syncthreads();
  for (int g = 0; g < 16; ++g) {
    const int cb = g << 2;
    for (int j = cb; j < cb + 4; ++j) {  // rank-1 strip, cols [cb,cb+4)
      if (t > j && t < h) {
        float inv = 1.0f / pan[j * 65 + j];
        float m = pan[t * 65 + j] * inv;
        for (int c = j + 1; c < cb + 4; ++c)
          pan[t * 65 + c] -= m * pan[c * 65 + j];
      }
      __syncthreads();
    }
    float rq0 = rsqrtf(pan[(cb + 0) * 65 + cb + 0]);
    float rq1 = rsqrtf(pan[(cb + 1) * 65 + cb + 1]);
    float rq2 = rsqrtf(pan[(cb + 2) * 65 + cb + 2]);
    float rq3 = rsqrtf(pan[(cb + 3) * 65 + cb + 3]);
    __syncthreads();
    if (t < h) {  // scale the 4 columns -> true L values
      if (t >= cb + 0) pan[t * 65 + cb + 0] *= rq0;
      if (t >= cb + 1) pan[t * 65 + cb + 1] *= rq1;
      if (t >= cb + 2) pan[t * 65 + cb + 2] *= rq2;
      if (t >= cb + 3) pan[t * 65 + cb + 3] *= rq3;
    }
    __syncthreads();
    if (t < h && t >= cb + 4) {  // rank-4 update of remaining panel cols
      const float m0 = pan[t * 65 + cb + 0], m1 = pan[t * 65 + cb + 1];
      const float m2 = pan[t * 65 + cb + 2], m3 = pan[t * 65 + cb + 3];
      for (int c = cb + 4; c <= t && c < 64; ++c) {
        float p0v = pan[c * 65 + cb + 0], p1v = pan[c * 65 + cb + 1];
        float p2v = pan[c * 65 + cb + 2], p3v = pan[c * 65 + cb + 3];
        pan[t * 65 + c] -= m0 * p0v + m1 * p1v + m2 * p2v + m3 * p3v;
      }
    }
    __syncthreads();
  }
  for (int idx = t; idx < (h << 6); idx += 512) {
    int r = idx >> 6, c = idx & 63;
    Am[(size_t)(p0 + r) * 512 + p0 + c] = pan[r * 65 + c];
  }
  for (int c = 0; c < 64; ++c)
    for (int r = t; r < h; r += 512)
      LT[(size_t)(p0 + c) * 512 + p0 + r] = pan[r * 65 + c];
}

// ---------------- trailing SYRK update: A22 -= Lp Lp^T ----------------------
__global__ __launch_bounds__(256) void chol_trail(float* __restrict__ Am, int p0)
{
  __shared__ float Lr[64 * 65];
  __shared__ float Lc[64 * 65];
  const int t = threadIdx.x;
  const int t0 = p0 + 64;
  const int r0 = t0 + (blockIdx.y << 6), c0 = t0 + (blockIdx.x << 6);
  for (int idx = t; idx < 4096; idx += 256) {
    int r = idx >> 6, c = idx & 63;
    Lr[r * 65 + c] = Am[(size_t)(r0 + r) * 512 + p0 + c];
    Lc[r * 65 + c] = Am[(size_t)(c0 + r) * 512 + p0 + c];
  }
  __syncthreads();
  const int ti = t >> 4, tj = t & 15;
  float acc[4][4] = {};
  for (int k = 0; k < 64; ++k) {
    float av[4], bv[4];
#pragma unroll
    for (int a = 0; a < 4; ++a) av[a] = Lr[(ti * 4 + a) * 65 + k];
#pragma unroll
    for (int b = 0; b < 4; ++b) bv[b] = Lc[(tj * 4 + b) * 65 + k];
#pragma unroll
    for (int a = 0; a < 4; ++a)
#pragma unroll
      for (int b = 0; b < 4; ++b) acc[a][b] += av[a] * bv[b];
  }
#pragma unroll
  for (int a = 0; a < 4; ++a) {
    size_t base = (size_t)(r0 + ti * 4 + a) * 512 + c0 + tj * 4;
    float4* p = (float4*)&Am[base];
    float4 cur = *p;
    cur.x -= acc[a][0]; cur.y -= acc[a][1]; cur.z -= acc[a][2]; cur.w -= acc[a][3];
    *p = cur;
  }
}

// ---------------- blocked TRSM: solve L L^T X = RT (10 RHS) -----------------
__global__ __launch_bounds__(512) void trsm_k(const float* __restrict__ Am,
    const float* __restrict__ LT, const float* __restrict__ RT,
    const float* __restrict__ Wout, const int* __restrict__ mode,
    float* __restrict__ X)
{
  const int t = threadIdx.x;
  if (*mode != 1) {  // eval mode: W stays W_out
    for (int idx = t; idx < 5120; idx += 512) {
      int i = idx / 10, c = idx - i * 10;
      X[idx] = Wout[c * 512 + i];
    }
    return;
  }
  __shared__ float Y[5120];
  __shared__ float Ld[64 * 65];
  for (int idx = t; idx < 5120; idx += 512) Y[idx] = RT[idx];
  // forward: L y = rt
  for (int p = 0; p < 8; ++p) {
    const int p0 = p << 6;
    for (int k0 = 0; k0 < p0; k0 += 64) {
      __syncthreads();
      for (int idx = t; idx < 4096; idx += 512)
        Ld[(idx >> 6) * 65 + (idx & 63)] = Am[(size_t)(p0 + (idx >> 6)) * 512 + k0 + (idx & 63)];
      __syncthreads();
      for (int idx = t; idx < 640; idx += 512) {
        int r = idx / 10, c = idx - r * 10;
        float s = Y[(p0 + r) * 10 + c];
        for (int kk = 0; kk < 64; ++kk)
          s -= Ld[r * 65 + kk] * Y[(k0 + kk) * 10 + c];
        Y[(p0 + r) * 10 + c] = s;
      }
    }
    __syncthreads();
    for (int idx = t; idx < 4096; idx += 512)
      Ld[(idx >> 6) * 65 + (idx & 63)] = Am[(size_t)(p0 + (idx >> 6)) * 512 + p0 + (idx & 63)];
    __syncthreads();
    if (t < 64) {  // wave-synchronous 64x64 triangle (no barriers)
      float y[10];
#pragma unroll
      for (int c = 0; c < 10; ++c) y[c] = Y[(p0 + t) * 10 + c];
      for (int j = 0; j < 64; ++j) {
        float inv = 1.0f / Ld[j * 65 + j];
        if (t == j) {
#pragma unroll
          for (int c = 0; c < 10; ++c) y[c] *= inv;
        }
        float lrj = Ld[t * 65 + j];
#pragma unroll
        for (int c = 0; c < 10; ++c) {
          float yj = __shfl(y[c], j, 64);
          if (t > j) y[c] -= lrj * yj;
        }
      }
#pragma unroll
      for (int c = 0; c < 10; ++c) Y[(p0 + t) * 10 + c] = y[c];
    }
    __syncthreads();
  }
  // backward: L^T x = y   (U rows = LT rows, contiguous)
  for (int p = 7; p >= 0; --p) {
    const int p0 = p << 6;
    for (int k0 = p0 + 64; k0 < 512; k0 += 64) {
      __syncthreads();
      for (int idx = t; idx < 4096; idx += 512)
        Ld[(idx >> 6) * 65 + (idx & 63)] = LT[(size_t)(p0 + (idx >> 6)) * 512 + k0 + (idx & 63)];
      __syncthreads();
      for (int idx = t; idx < 640; idx += 512) {
        int r = idx / 10, c = idx - r * 10;
        float s = Y[(p0 + r) * 10 + c];
        for (int kk = 0; kk < 64; ++kk)
          s -= Ld[r * 65 + kk] * Y[(k0 + kk) * 10 + c];
        Y[(p0 + r) * 10 + c] = s;
      }
    }
    __syncthreads();
    for (int idx = t; idx < 4096; idx += 512)
      Ld[(idx >> 6) * 65 + (idx & 63)] = LT[(size_t)(p0 + (idx >> 6)) * 512 + p0 + (idx & 63)];
    __syncthreads();
    if (t < 64) {
      float y[10];
#pragma unroll
      for (int c = 0; c < 10; ++c) y[c] = Y[(p0 + t) * 10 + c];
      for (int j = 63; j >= 0; --j) {
        float inv = 1.0f / Ld[j * 65 + j];
        if (t == j) {
#pragma unroll
          for (int c = 0; c < 10; ++c) y[c] *= inv;
        }
        float urj = Ld[t * 65 + j];
#pragma unroll
        for (int c = 0; c < 10; ++c) {
          float yj = __shfl(y[c], j, 64);
          if (t < j) y[c] -= urj * yj;
        }
      }
#pragma unroll
      for (int c = 0; c < 10; ++c) Y[(p0 + t) * 10 + c] = y[c];
    }
    __syncthreads();
  }
  for (int idx = t; idx < 5120; idx += 512) X[idx] = Y[idx];
}

// ---------------- prediction = z @ X  (X = W^T, [512][10]) ------------------
__global__ __launch_bounds__(256) void pred_k(const float* __restrict__ z,
    const float* __restrict__ X, float* __restrict__ pred)
{
  __shared__ float xs[5120];
  __shared__ float zs[64 * 65];
  __shared__ float part[2560];
  const int t = threadIdx.x;
  const int b0 = blockIdx.x << 6;
  for (int idx = t; idx < 5120; idx += 256) xs[idx] = X[idx];
  const int rl = t & 63, q = t >> 6;
  float pa[10] = {};
  for (int i0 = 0; i0 < 512; i0 += 64) {
    __syncthreads();
    for (int idx = t; idx < 4096; idx += 256)
      zs[(idx >> 6) * 65 + (idx & 63)] = z[(size_t)(b0 + (idx >> 6)) * 512 + i0 + (idx & 63)];
    __syncthreads();
    for (int iq = 0; iq < 16; ++iq) {
      int ii = (q << 4) + iq;
      float zv = zs[rl * 65 + ii];
#pragma unroll
      for (int c = 0; c < 10; ++c) pa[c] += zv * xs[(i0 + ii) * 10 + c];
    }
  }
  __syncthreads();
#pragma unroll
  for (int c = 0; c < 10; ++c) part[(rl * 4 + q) * 10 + c] = pa[c];
  __syncthreads();
  for (int idx = t; idx < 640; idx += 256) {
    int r = idx / 10, c = idx - r * 10;
    float s = part[(r * 4 + 0) * 10 + c] + part[(r * 4 + 1) * 10 + c] +
              part[(r * 4 + 2) * 10 + c] + part[(r * 4 + 3) * 10 + c];
    pred[(size_t)(b0 + r) * 10 + c] = s;
  }
}

// ============================================================================
extern "C" void kernel_launch(void* const* d_in, const int* in_sizes, int n_in,
                              void* d_out, int out_size, void* d_ws, size_t ws_size,
                              hipStream_t stream)
{
  const float* data  = (const float*)d_in[0];
  const float* label = (const float*)d_in[1];
  const float* eps   = (const float*)d_in[2];
  const float* W_e1  = (const float*)d_in[3];
  const float* b_e1  = (const float*)d_in[4];
  const float* W_e2  = (const float*)d_in[5];
  const float* b_e2  = (const float*)d_in[6];
  const float* W_mu  = (const float*)d_in[7];
  const float* b_mu  = (const float*)d_in[8];
  const float* W_lv  = (const float*)d_in[9];
  const float* b_lv  = (const float*)d_in[10];
  const float* W_d1  = (const float*)d_in[11];
  const float* b_d1  = (const float*)d_in[12];
  const float* W_d2  = (const float*)d_in[13];
  const float* b_d2  = (const float*)d_in[14];
  const float* W_out = (const float*)d_in[15];
  const int*   mode  = (const int*)d_in[17];

  float* out    = (float*)d_out;
  float* o_enc  = out;                          // [2048,512]
  float* o_mu   = out + 1048576;                // [2048,512]
  float* o_lv   = out + 2097152;                // [2048,512]
  float* o_z    = out + 3145728;                // [2048,512]
  float* o_dec  = out + 4194304;                // [2048,4096]
  float* o_pred = out + 12582912;               // [2048,10]

  char* ws = (char*)d_ws;
  const size_t MB = 1u << 20;
  unsigned short* bfD   = (unsigned short*)(ws + 0 * MB);   // 16 MB (later reused for W_d2 bf16)
  unsigned short* bfWe1 = (unsigned short*)(ws + 16 * MB);  // 16 MB (later reused for d1 bf16)
  unsigned short* h1b   = (unsigned short*)(ws + 32 * MB);  // 8 MB
  unsigned short* bfWe2 = (unsigned short*)(ws + 40 * MB);  // 2 MB
  unsigned short* encb  = (unsigned short*)(ws + 42 * MB);  // 2 MB
  unsigned short* bfWmu = (unsigned short*)(ws + 44 * MB);  // 0.5 MB
  unsigned short* bfWlv = (unsigned short*)(ws + 44 * MB + 512 * 1024);
  unsigned short* zb    = (unsigned short*)(ws + 45 * MB);  // 2 MB
  unsigned short* bfWd1 = (unsigned short*)(ws + 47 * MB);  // 2 MB
  unsigned short* bfWd2 = bfD;    // alias: data bf16 dead after GEMM1
  unsigned short* d1b   = bfWe1;  // alias: W_e1 bf16 dead after GEMM1
  float* Amat = (float*)(ws + 49 * MB);          // 1 MB
  float* LTm  = (float*)(ws + 50 * MB);          // 1 MB
  float* RTm  = (float*)(ws + 51 * MB);          // 20 KB
  float* Xm   = (float*)(ws + 51 * MB + 65536);  // 20 KB

  // encoder
  f2bf_k<<<8192, 256, 0, stream>>>(data, bfD);
  f2bf_k<<<8192, 256, 0, stream>>>(W_e1, bfWe1);
  gemm_nt<1,0,1><<<dim3(16,16), 256, 0, stream>>>(bfD, bfWe1, b_e1, nullptr, h1b, 2048, 4096);
  f2bf_k<<<1024, 256, 0, stream>>>(W_e2, bfWe2);
  gemm_nt<1,1,1><<<dim3(4,16), 256, 0, stream>>>(h1b, bfWe2, b_e2, o_enc, encb, 512, 2048);
  // mu / logvar / z
  f2bf_k<<<256, 256, 0, stream>>>(W_mu, bfWmu);
  f2bf_k<<<256, 256, 0, stream>>>(W_lv, bfWlv);
  gemm_nt<0,1,0><<<dim3(4,16), 256, 0, stream>>>(encb, bfWmu, b_mu, o_mu, nullptr, 512, 512);
  gemm_nt<0,1,0><<<dim3(4,16), 256, 0, stream>>>(encb, bfWlv, b_lv, o_lv, nullptr, 512, 512);
  z_k<<<1024, 256, 0, stream>>>(o_mu, o_lv, eps, o_z, zb);
  // decoder
  f2bf_k<<<1024, 256, 0, stream>>>(W_d1, bfWd1);
  gemm_nt<1,0,1><<<dim3(16,16), 256, 0, stream>>>(zb, bfWd1, b_d1, nullptr, d1b, 2048, 512);
  f2bf_k<<<8192, 256, 0, stream>>>(W_d2, bfWd2);
  gemm_nt<0,1,0><<<dim3(32,16), 256, 0, stream>>>(d1b, bfWd2, b_d2, o_dec, nullptr, 4096, 2048);
  // RLS closed form: A = 0.01 I + z^T z ; RT = z^T label + 0.01 Wout^T
  gram_k<<<dim3(8,8), 256, 0, stream>>>(o_z, Amat);
  rhs_k<<<8, 256, 0, stream>>>(o_z, label, W_out, RTm);
  // Cholesky A = L L^T (blocked right-looking)
  for (int p = 0; p < 8; ++p) {
    chol_panel<<<1, 512, 0, stream>>>(Amat, LTm, p * 64);
    int nb = 7 - p;
    if (nb > 0) chol_trail<<<dim3(nb, nb), 256, 0, stream>>>(Amat, p * 64);
  }
  trsm_k<<<1, 512, 0, stream>>>(Amat, LTm, RTm, W_out, mode, Xm);
  pred_k<<<32, 256, 0, stream>>>(o_z, Xm, o_pred);
}

// Round 2
// 1358.443 us; speedup vs baseline: 1.2592x; 1.2592x over previous
//
#include <hip/hip_runtime.h>
#include <hip/hip_bf16.h>
#include <cstdint>
#include <cstddef>

// Problem constants: B=2048, D=4096, H=2048, L=512, C=10, RLS_INIT=100
// Key math: RLS scan == solve  A W^T = R^T  with
//   A = 0.01*I + z^T z   (all 10 class P's are identical!)
//   R = 0.01*W_out + label^T z
// => prediction = z @ A^{-1} R^T
// A is SPD, kappa ~ 9 => Newton-Schulz inverse: Y0 = I/gersh(A),
// Y_{k+1} = Y_k (2I - A Y_k), 12 iters -> fp32-exact. Fully parallel GEMMs,
// replaces the 488us serial trsm + ~240us serial Cholesky panel chain.

#define DEV __device__ __forceinline__

typedef __attribute__((ext_vector_type(8))) short bf16x8;
typedef __attribute__((ext_vector_type(4))) float f32x4;

DEV unsigned short f2b(float f) {  // fp32 -> bf16 round-to-nearest-even
  unsigned u = __builtin_bit_cast(unsigned, f);
  u += 0x7FFFu + ((u >> 16) & 1u);
  return (unsigned short)(u >> 16);
}

DEV void load_lds16(void* l, const void* g) {  // async global->LDS, 16B/lane
  __builtin_amdgcn_global_load_lds(
      (const __attribute__((address_space(1))) unsigned int*)g,
      (__attribute__((address_space(3))) unsigned int*)l, 16, 0, 0);
}

// ---------------- fp32 -> bf16 convert (vectorized, exact grid) --------------
__global__ __launch_bounds__(256) void f2bf_k(const float* __restrict__ in,
                                              unsigned short* __restrict__ out) {
  int i = blockIdx.x * 256 + threadIdx.x;
  float4 v = ((const float4*)in)[i];
  ushort4 o;
  o.x = f2b(v.x); o.y = f2b(v.y); o.z = f2b(v.z); o.w = f2b(v.w);
  ((ushort4*)out)[i] = o;
}

// ---------------- bf16 MFMA GEMM: C = act(A[M,K] @ B[N,K]^T + bias) ---------
// 128x128 tile, BK=32, 4 waves (2x2), each wave 64x64 (4x4 frags of 16x16x32).
template<int RELU, int WF32, int WBF16>
__global__ __launch_bounds__(256) void gemm_nt(
    const unsigned short* __restrict__ A, const unsigned short* __restrict__ Bm,
    const float* __restrict__ bias, float* __restrict__ Cf,
    unsigned short* __restrict__ Cb, int N, int K)
{
  __shared__ unsigned short lA[4096];
  __shared__ unsigned short lB[4096];
  const int t = threadIdx.x;
  const int l = t & 63, w = t >> 6;
  const int r0 = blockIdx.y << 7, c0 = blockIdx.x << 7;
  const int srow = (w << 4) + (l >> 2);   // staging row within 64-row chunk
  const int scol = (l & 3) << 3;          // k offset (elems)
  const unsigned short* gA = A + (size_t)(r0 + srow) * K + scol;
  const unsigned short* gB = Bm + (size_t)(c0 + srow) * K + scol;
  unsigned short* dA = lA + (w << 9);     // wave-uniform LDS base
  unsigned short* dB = lB + (w << 9);
  const size_t q1 = (size_t)64 * K;
  f32x4 acc[4][4] = {};
  const int wm = (w >> 1) << 6, wn = (w & 1) << 6;
  const int fr = l & 15;
  const int fk = (l >> 4) << 3;
  for (int k0 = 0; k0 < K; k0 += 32) {
    load_lds16(dA,        gA + k0);
    load_lds16(dA + 2048, gA + k0 + q1);
    load_lds16(dB,        gB + k0);
    load_lds16(dB + 2048, gB + k0 + q1);
    asm volatile("s_waitcnt vmcnt(0)" ::: "memory");
    __syncthreads();
    bf16x8 av[4], bv[4];
#pragma unroll
    for (int mi = 0; mi < 4; ++mi)
      av[mi] = *(const bf16x8*)(lA + ((wm + (mi << 4) + fr) << 5) + fk);
#pragma unroll
    for (int ni = 0; ni < 4; ++ni)
      bv[ni] = *(const bf16x8*)(lB + ((wn + (ni << 4) + fr) << 5) + fk);
#pragma unroll
    for (int mi = 0; mi < 4; ++mi)
#pragma unroll
      for (int ni = 0; ni < 4; ++ni)
        acc[mi][ni] = __builtin_amdgcn_mfma_f32_16x16x32_bf16(av[mi], bv[ni], acc[mi][ni], 0, 0, 0);
    __syncthreads();
  }
  // epilogue: C/D layout col=lane&15, row=(lane>>4)*4+reg  [m89-verified]
#pragma unroll
  for (int mi = 0; mi < 4; ++mi) {
    const int row = r0 + wm + (mi << 4) + ((l >> 4) << 2);
#pragma unroll
    for (int ni = 0; ni < 4; ++ni) {
      const int col = c0 + wn + (ni << 4) + (l & 15);
      const float bvs = bias[col];
#pragma unroll
      for (int r = 0; r < 4; ++r) {
        float v = acc[mi][ni][r] + bvs;
        if (RELU) v = v > 0.f ? v : 0.f;
        const size_t idx = (size_t)(row + r) * N + col;
        if (WF32) Cf[idx] = v;
        if (WBF16) Cb[idx] = f2b(v);
      }
    }
  }
}

// ---------------- z = mu + eps * exp(0.5*logvar) ----------------------------
__global__ __launch_bounds__(256) void z_k(const float* __restrict__ mu,
    const float* __restrict__ lv, const float* __restrict__ eps,
    float* __restrict__ z, unsigned short* __restrict__ zb)
{
  int i = blockIdx.x * 256 + threadIdx.x;
  float4 m = ((const float4*)mu)[i];
  float4 v = ((const float4*)lv)[i];
  float4 e = ((const float4*)eps)[i];
  float4 r;
  r.x = m.x + e.x * expf(0.5f * v.x);
  r.y = m.y + e.y * expf(0.5f * v.y);
  r.z = m.z + e.z * expf(0.5f * v.z);
  r.w = m.w + e.w * expf(0.5f * v.w);
  ((float4*)z)[i] = r;
  ushort4 o; o.x = f2b(r.x); o.y = f2b(r.y); o.z = f2b(r.z); o.w = f2b(r.w);
  ((ushort4*)zb)[i] = o;
}

// ---------------- A = 0.01*I + z^T z  (fp32, 64x64 tiles) -------------------
__global__ __launch_bounds__(256) void gram_k(const float* __restrict__ z,
                                              float* __restrict__ Am)
{
  __shared__ float zi[64 * 65];
  __shared__ float zj[64 * 65];
  const int t = threadIdx.x;
  const int i0 = blockIdx.y << 6, j0 = blockIdx.x << 6;
  const int ti = t >> 4, tj = t & 15;
  float acc[4][4] = {};
  for (int b0 = 0; b0 < 2048; b0 += 64) {
    __syncthreads();
    for (int idx = t; idx < 4096; idx += 256) {
      int r = idx >> 6, c = idx & 63;
      zi[r * 65 + c] = z[(size_t)(b0 + r) * 512 + i0 + c];
      zj[r * 65 + c] = z[(size_t)(b0 + r) * 512 + j0 + c];
    }
    __syncthreads();
    for (int bb = 0; bb < 64; ++bb) {
      float av[4], bv[4];
#pragma unroll
      for (int a = 0; a < 4; ++a) av[a] = zi[bb * 65 + ti * 4 + a];
#pragma unroll
      for (int b = 0; b < 4; ++b) bv[b] = zj[bb * 65 + tj * 4 + b];
#pragma unroll
      for (int a = 0; a < 4; ++a)
#pragma unroll
        for (int b = 0; b < 4; ++b) acc[a][b] += av[a] * bv[b];
    }
  }
#pragma unroll
  for (int a = 0; a < 4; ++a)
#pragma unroll
    for (int b = 0; b < 4; ++b) {
      int gi = i0 + ti * 4 + a, gj = j0 + tj * 4 + b;
      float v = acc[a][b];
      if (gi == gj) v += 0.01f;
      Am[(size_t)gi * 512 + gj] = v;
    }
}

// ---------------- RT[i][c] = sum_b label[b][c] z[b][i] + 0.01*Wout[c][i] ----
__global__ __launch_bounds__(256) void rhs_k(const float* __restrict__ z,
    const float* __restrict__ label, const float* __restrict__ Wout,
    float* __restrict__ RT)
{
  __shared__ float zt[64 * 65];
  __shared__ float lb[640];
  const int t = threadIdx.x;
  const int i0 = blockIdx.x << 6;
  const int w = t >> 6, il = t & 63;
  float a0 = 0.f, a1 = 0.f, a2 = 0.f;
  for (int b0 = 0; b0 < 2048; b0 += 64) {
    __syncthreads();
    for (int idx = t; idx < 4096; idx += 256)
      zt[(idx >> 6) * 65 + (idx & 63)] = z[(size_t)(b0 + (idx >> 6)) * 512 + i0 + (idx & 63)];
    for (int idx = t; idx < 640; idx += 256) lb[idx] = label[b0 * 10 + idx];
    __syncthreads();
    for (int bb = 0; bb < 64; ++bb) {
      float zv = zt[bb * 65 + il];
      a0 += zv * lb[bb * 10 + w];
      a1 += zv * lb[bb * 10 + w + 4];
      if (w < 2) a2 += zv * lb[bb * 10 + w + 8];
    }
  }
  int i = i0 + il;
  RT[i * 10 + w]     = a0 + 0.01f * Wout[w * 512 + i];
  RT[i * 10 + w + 4] = a1 + 0.01f * Wout[(w + 4) * 512 + i];
  if (w < 2) RT[i * 10 + w + 8] = a2 + 0.01f * Wout[(w + 8) * 512 + i];
}

// ---------------- zero the Gershgorin scalar --------------------------------
__global__ void zero_k(unsigned* __restrict__ g) { g[0] = 0u; }

// ---------------- g = max_i sum_j |A[i][j]|  (>= lambda_max) ----------------
__global__ __launch_bounds__(256) void gersh_k(const float* __restrict__ A,
                                               unsigned* __restrict__ g)
{
  const int w = threadIdx.x >> 6, l = threadIdx.x & 63;
  const int row = blockIdx.x * 4 + w;
  const float* ar = A + (size_t)row * 512;
  float s = 0.f;
  for (int j = l; j < 512; j += 64) s += fabsf(ar[j]);
#pragma unroll
  for (int o = 32; o; o >>= 1) s += __shfl_xor(s, o, 64);
  if (l == 0) atomicMax(g, __builtin_bit_cast(unsigned, s));  // positive floats: bits monotone
}

// ---------------- Y0 = (1/g) * I --------------------------------------------
__global__ __launch_bounds__(256) void ns_init_k(const unsigned* __restrict__ g,
                                                 float* __restrict__ Y)
{
  const float alpha = 1.0f / __builtin_bit_cast(float, g[0]);
  int i = blockIdx.x * 256 + threadIdx.x;
  int base = i * 4;
  int row = base >> 9, col = base & 511;
  float4 v = {0.f, 0.f, 0.f, 0.f};
  int d = row - col;
  if (d >= 0 && d < 4) ((float*)&v)[d] = alpha;
  ((float4*)Y)[i] = v;
}

// ---------------- fp32 GEMM 512x512x512: D = A*B  (TWOI: D = 2I - A*B) ------
// 32x32 tile per block, grid 16x16=256 blocks, 2x2 micro, float2 LDS reads.
template<int TWOI>
__global__ __launch_bounds__(256) void nsgemm_k(const float* __restrict__ A,
    const float* __restrict__ Bm, float* __restrict__ D)
{
  __shared__ float sAT[64 * 34];  // [k][row], transposed A tile, pad 34
  __shared__ float sB[64 * 34];   // [k][col], pad 34
  const int t = threadIdx.x;
  const int i0 = blockIdx.y << 5, j0 = blockIdx.x << 5;
  const int ti = t >> 4, tj = t & 15;
  float acc00 = 0.f, acc01 = 0.f, acc10 = 0.f, acc11 = 0.f;
  for (int k0 = 0; k0 < 512; k0 += 64) {
    __syncthreads();
    for (int idx = t; idx < 2048; idx += 256) {
      int r = idx >> 6, c = idx & 63;     // A: 32 rows x 64 k (coalesced read)
      sAT[c * 34 + r] = A[(size_t)(i0 + r) * 512 + k0 + c];
      int rb = idx >> 5, cb = idx & 31;   // B: 64 k x 32 cols
      sB[rb * 34 + cb] = Bm[(size_t)(k0 + rb) * 512 + j0 + cb];
    }
    __syncthreads();
#pragma unroll 8
    for (int kk = 0; kk < 64; ++kk) {
      float2 av = *(const float2*)&sAT[kk * 34 + ti * 2];
      float2 bv = *(const float2*)&sB[kk * 34 + tj * 2];
      acc00 += av.x * bv.x; acc01 += av.x * bv.y;
      acc10 += av.y * bv.x; acc11 += av.y * bv.y;
    }
  }
  const int gi0 = i0 + ti * 2, gj0 = j0 + tj * 2;
  float2 r0 = {acc00, acc01}, r1 = {acc10, acc11};
  if (TWOI) {
    r0.x = (gi0 == gj0 ? 2.f : 0.f) - r0.x;
    r0.y = (gi0 == gj0 + 1 ? 2.f : 0.f) - r0.y;
    r1.x = (gi0 + 1 == gj0 ? 2.f : 0.f) - r1.x;
    r1.y = (gi0 + 1 == gj0 + 1 ? 2.f : 0.f) - r1.y;
  }
  *(float2*)&D[(size_t)gi0 * 512 + gj0] = r0;
  *(float2*)&D[(size_t)(gi0 + 1) * 512 + gj0] = r1;
}

// ---------------- X[i][c] = sum_j Y[i][j] RT[j][c]  (or Wout^T in eval) -----
__global__ __launch_bounds__(256) void xform_k(const float* __restrict__ Y,
    const float* __restrict__ RT, const float* __restrict__ Wout,
    const int* __restrict__ mode, float* __restrict__ X)
{
  __shared__ float yt[64 * 65];
  __shared__ float rt[640];
  const int t = threadIdx.x;
  const int i0 = blockIdx.x << 6;
  const int w = t >> 6, il = t & 63;
  float a0 = 0.f, a1 = 0.f, a2 = 0.f;
  for (int j0 = 0; j0 < 512; j0 += 64) {
    __syncthreads();
    for (int idx = t; idx < 4096; idx += 256)
      yt[(idx >> 6) * 65 + (idx & 63)] = Y[(size_t)(i0 + (idx >> 6)) * 512 + j0 + (idx & 63)];
    for (int idx = t; idx < 640; idx += 256) rt[idx] = RT[j0 * 10 + idx];
    __syncthreads();
    for (int jj = 0; jj < 64; ++jj) {
      float yv = yt[il * 65 + jj];
      a0 += yv * rt[jj * 10 + w];
      a1 += yv * rt[jj * 10 + w + 4];
      if (w < 2) a2 += yv * rt[jj * 10 + w + 8];
    }
  }
  const int i = i0 + il;
  const bool train = (*mode == 1);
  X[i * 10 + w]     = train ? a0 : Wout[w * 512 + i];
  X[i * 10 + w + 4] = train ? a1 : Wout[(w + 4) * 512 + i];
  if (w < 2) X[i * 10 + w + 8] = train ? a2 : Wout[(w + 8) * 512 + i];
}

// ---------------- prediction = z @ X  (X = W^T, [512][10]) ------------------
__global__ __launch_bounds__(256) void pred_k(const float* __restrict__ z,
    const float* __restrict__ X, float* __restrict__ pred)
{
  __shared__ float xs[5120];
  __shared__ float zs[64 * 65];
  __shared__ float part[2560];
  const int t = threadIdx.x;
  const int b0 = blockIdx.x << 6;
  for (int idx = t; idx < 5120; idx += 256) xs[idx] = X[idx];
  const int rl = t & 63, q = t >> 6;
  float pa[10] = {};
  for (int i0 = 0; i0 < 512; i0 += 64) {
    __syncthreads();
    for (int idx = t; idx < 4096; idx += 256)
      zs[(idx >> 6) * 65 + (idx & 63)] = z[(size_t)(b0 + (idx >> 6)) * 512 + i0 + (idx & 63)];
    __syncthreads();
    for (int iq = 0; iq < 16; ++iq) {
      int ii = (q << 4) + iq;
      float zv = zs[rl * 65 + ii];
#pragma unroll
      for (int c = 0; c < 10; ++c) pa[c] += zv * xs[(i0 + ii) * 10 + c];
    }
  }
  __syncthreads();
#pragma unroll
  for (int c = 0; c < 10; ++c) part[(rl * 4 + q) * 10 + c] = pa[c];
  __syncthreads();
  for (int idx = t; idx < 640; idx += 256) {
    int r = idx / 10, c = idx - r * 10;
    float s = part[(r * 4 + 0) * 10 + c] + part[(r * 4 + 1) * 10 + c] +
              part[(r * 4 + 2) * 10 + c] + part[(r * 4 + 3) * 10 + c];
    pred[(size_t)(b0 + r) * 10 + c] = s;
  }
}

// ============================================================================
extern "C" void kernel_launch(void* const* d_in, const int* in_sizes, int n_in,
                              void* d_out, int out_size, void* d_ws, size_t ws_size,
                              hipStream_t stream)
{
  const float* data  = (const float*)d_in[0];
  const float* label = (const float*)d_in[1];
  const float* eps   = (const float*)d_in[2];
  const float* W_e1  = (const float*)d_in[3];
  const float* b_e1  = (const float*)d_in[4];
  const float* W_e2  = (const float*)d_in[5];
  const float* b_e2  = (const float*)d_in[6];
  const float* W_mu  = (const float*)d_in[7];
  const float* b_mu  = (const float*)d_in[8];
  const float* W_lv  = (const float*)d_in[9];
  const float* b_lv  = (const float*)d_in[10];
  const float* W_d1  = (const float*)d_in[11];
  const float* b_d1  = (const float*)d_in[12];
  const float* W_d2  = (const float*)d_in[13];
  const float* b_d2  = (const float*)d_in[14];
  const float* W_out = (const float*)d_in[15];
  const int*   mode  = (const int*)d_in[17];

  float* out    = (float*)d_out;
  float* o_enc  = out;                          // [2048,512]
  float* o_mu   = out + 1048576;                // [2048,512]
  float* o_lv   = out + 2097152;                // [2048,512]
  float* o_z    = out + 3145728;                // [2048,512]
  float* o_dec  = out + 4194304;                // [2048,4096]
  float* o_pred = out + 12582912;               // [2048,10]

  char* ws = (char*)d_ws;
  const size_t MB = 1u << 20;
  unsigned short* bfD   = (unsigned short*)(ws + 0 * MB);   // 16 MB (reused: W_d2 bf16, then NS buffers)
  unsigned short* bfWe1 = (unsigned short*)(ws + 16 * MB);  // 16 MB (reused: d1 bf16)
  unsigned short* h1b   = (unsigned short*)(ws + 32 * MB);  // 8 MB
  unsigned short* bfWe2 = (unsigned short*)(ws + 40 * MB);  // 2 MB
  unsigned short* encb  = (unsigned short*)(ws + 42 * MB);  // 2 MB
  unsigned short* bfWmu = (unsigned short*)(ws + 44 * MB);  // 0.5 MB
  unsigned short* bfWlv = (unsigned short*)(ws + 44 * MB + 512 * 1024);
  unsigned short* zb    = (unsigned short*)(ws + 45 * MB);  // 2 MB
  unsigned short* bfWd1 = (unsigned short*)(ws + 47 * MB);  // 2 MB
  unsigned short* bfWd2 = bfD;    // alias: data bf16 dead after GEMM1
  unsigned short* d1b   = bfWe1;  // alias: W_e1 bf16 dead after GEMM1
  float* Amat = (float*)(ws + 49 * MB);          // 1 MB
  float* RTm  = (float*)(ws + 51 * MB);          // 20 KB
  float* Xm   = (float*)(ws + 51 * MB + 65536);  // 20 KB
  // NS buffers alias bfD region (dead after GEMM5, before gram/NS run):
  float* Ya = (float*)(ws + 0 * MB);             // 1 MB
  float* Yb = (float*)(ws + 1 * MB);             // 1 MB
  float* Sm = (float*)(ws + 2 * MB);             // 1 MB
  unsigned* gmax = (unsigned*)(ws + 3 * MB);     // 4 B

  // encoder
  f2bf_k<<<8192, 256, 0, stream>>>(data, bfD);
  f2bf_k<<<8192, 256, 0, stream>>>(W_e1, bfWe1);
  gemm_nt<1,0,1><<<dim3(16,16), 256, 0, stream>>>(bfD, bfWe1, b_e1, nullptr, h1b, 2048, 4096);
  f2bf_k<<<1024, 256, 0, stream>>>(W_e2, bfWe2);
  gemm_nt<1,1,1><<<dim3(4,16), 256, 0, stream>>>(h1b, bfWe2, b_e2, o_enc, encb, 512, 2048);
  // mu / logvar / z
  f2bf_k<<<256, 256, 0, stream>>>(W_mu, bfWmu);
  f2bf_k<<<256, 256, 0, stream>>>(W_lv, bfWlv);
  gemm_nt<0,1,0><<<dim3(4,16), 256, 0, stream>>>(encb, bfWmu, b_mu, o_mu, nullptr, 512, 512);
  gemm_nt<0,1,0><<<dim3(4,16), 256, 0, stream>>>(encb, bfWlv, b_lv, o_lv, nullptr, 512, 512);
  z_k<<<1024, 256, 0, stream>>>(o_mu, o_lv, eps, o_z, zb);
  // decoder
  f2bf_k<<<1024, 256, 0, stream>>>(W_d1, bfWd1);
  gemm_nt<1,0,1><<<dim3(16,16), 256, 0, stream>>>(zb, bfWd1, b_d1, nullptr, d1b, 2048, 512);
  f2bf_k<<<8192, 256, 0, stream>>>(W_d2, bfWd2);
  gemm_nt<0,1,0><<<dim3(32,16), 256, 0, stream>>>(d1b, bfWd2, b_d2, o_dec, nullptr, 4096, 2048);
  // RLS closed form: A = 0.01 I + z^T z ; RT = z^T label + 0.01 Wout^T
  gram_k<<<dim3(8,8), 256, 0, stream>>>(o_z, Amat);
  rhs_k<<<8, 256, 0, stream>>>(o_z, label, W_out, RTm);
  // Newton-Schulz inverse: Y ~= A^{-1}
  zero_k<<<1, 1, 0, stream>>>(gmax);
  gersh_k<<<128, 256, 0, stream>>>(Amat, gmax);
  ns_init_k<<<256, 256, 0, stream>>>(gmax, Ya);
  float* Yc = Ya;
  for (int it = 0; it < 12; ++it) {
    nsgemm_k<1><<<dim3(16,16), 256, 0, stream>>>(Amat, Yc, Sm);      // S = 2I - A*Y
    float* Yn = (Yc == Ya) ? Yb : Ya;
    nsgemm_k<0><<<dim3(16,16), 256, 0, stream>>>(Yc, Sm, Yn);        // Y' = Y*S
    Yc = Yn;
  }
  // X = Y * RT (train) or Wout^T (eval); prediction = z @ X
  xform_k<<<8, 256, 0, stream>>>(Yc, RTm, W_out, mode, Xm);
  pred_k<<<32, 256, 0, stream>>>(o_z, Xm, o_pred);
}

// Round 3
// 1095.504 us; speedup vs baseline: 1.5614x; 1.2400x over previous
//
#include <hip/hip_runtime.h>
#include <hip/hip_bf16.h>
#include <cstdint>
#include <cstddef>

// B=2048, D=4096, H=2048, L=512, C=10, RLS_INIT=100
// RLS scan == solve A W^T = R^T, A = 0.01 I + z^T z (shared across classes),
// R = 0.01 W_out + label^T z; prediction = z A^{-1} R^T.
// A SPD, kappa~9 -> Newton-Schulz (10 iters, fp32 GEMMs).
// Round 3: gram via bf16 MFMA (+transpose), NS 12->10, rhs split-B atomics,
// XCD swizzle on MFMA GEMMs.

#define DEV __device__ __forceinline__

typedef __attribute__((ext_vector_type(8))) short bf16x8;
typedef __attribute__((ext_vector_type(4))) float f32x4;

DEV unsigned short f2b(float f) {  // fp32 -> bf16 RNE
  unsigned u = __builtin_bit_cast(unsigned, f);
  u += 0x7FFFu + ((u >> 16) & 1u);
  return (unsigned short)(u >> 16);
}

DEV void load_lds16(void* l, const void* g) {  // async global->LDS, 16B/lane
  __builtin_amdgcn_global_load_lds(
      (const __attribute__((address_space(1))) unsigned int*)g,
      (__attribute__((address_space(3))) unsigned int*)l, 16, 0, 0);
}

// XCD-aware bijective block swizzle (requires nwg%8==0) [T1]
DEV void xcd_swz(int& bx, int& by) {
  int gx = gridDim.x, nwg = gx * gridDim.y;
  int bid = by * gx + bx;
  int swz = (bid & 7) * (nwg >> 3) + (bid >> 3);
  bx = swz % gx; by = swz / gx;
}

// ---------------- fp32 -> bf16 convert --------------------------------------
__global__ __launch_bounds__(256) void f2bf_k(const float* __restrict__ in,
                                              unsigned short* __restrict__ out) {
  int i = blockIdx.x * 256 + threadIdx.x;
  float4 v = ((const float4*)in)[i];
  ushort4 o;
  o.x = f2b(v.x); o.y = f2b(v.y); o.z = f2b(v.z); o.w = f2b(v.w);
  ((ushort4*)out)[i] = o;
}

// ---------------- bf16 MFMA GEMM: C = act(A[M,K] @ B[N,K]^T + bias) ---------
template<int RELU, int WF32, int WBF16>
__global__ __launch_bounds__(256) void gemm_nt(
    const unsigned short* __restrict__ A, const unsigned short* __restrict__ Bm,
    const float* __restrict__ bias, float* __restrict__ Cf,
    unsigned short* __restrict__ Cb, int N, int K)
{
  __shared__ unsigned short lA[4096];
  __shared__ unsigned short lB[4096];
  const int t = threadIdx.x;
  const int l = t & 63, w = t >> 6;
  int bx = blockIdx.x, by = blockIdx.y;
  xcd_swz(bx, by);
  const int r0 = by << 7, c0 = bx << 7;
  const int srow = (w << 4) + (l >> 2);
  const int scol = (l & 3) << 3;
  const unsigned short* gA = A + (size_t)(r0 + srow) * K + scol;
  const unsigned short* gB = Bm + (size_t)(c0 + srow) * K + scol;
  unsigned short* dA = lA + (w << 9);
  unsigned short* dB = lB + (w << 9);
  const size_t q1 = (size_t)64 * K;
  f32x4 acc[4][4] = {};
  const int wm = (w >> 1) << 6, wn = (w & 1) << 6;
  const int fr = l & 15;
  const int fk = (l >> 4) << 3;
  for (int k0 = 0; k0 < K; k0 += 32) {
    load_lds16(dA,        gA + k0);
    load_lds16(dA + 2048, gA + k0 + q1);
    load_lds16(dB,        gB + k0);
    load_lds16(dB + 2048, gB + k0 + q1);
    asm volatile("s_waitcnt vmcnt(0)" ::: "memory");
    __syncthreads();
    bf16x8 av[4], bv[4];
#pragma unroll
    for (int mi = 0; mi < 4; ++mi)
      av[mi] = *(const bf16x8*)(lA + ((wm + (mi << 4) + fr) << 5) + fk);
#pragma unroll
    for (int ni = 0; ni < 4; ++ni)
      bv[ni] = *(const bf16x8*)(lB + ((wn + (ni << 4) + fr) << 5) + fk);
#pragma unroll
    for (int mi = 0; mi < 4; ++mi)
#pragma unroll
      for (int ni = 0; ni < 4; ++ni)
        acc[mi][ni] = __builtin_amdgcn_mfma_f32_16x16x32_bf16(av[mi], bv[ni], acc[mi][ni], 0, 0, 0);
    __syncthreads();
  }
#pragma unroll
  for (int mi = 0; mi < 4; ++mi) {
    const int row = r0 + wm + (mi << 4) + ((l >> 4) << 2);
#pragma unroll
    for (int ni = 0; ni < 4; ++ni) {
      const int col = c0 + wn + (ni << 4) + (l & 15);
      const float bvs = bias[col];
#pragma unroll
      for (int r = 0; r < 4; ++r) {
        float v = acc[mi][ni][r] + bvs;
        if (RELU) v = v > 0.f ? v : 0.f;
        const size_t idx = (size_t)(row + r) * N + col;
        if (WF32) Cf[idx] = v;
        if (WBF16) Cb[idx] = f2b(v);
      }
    }
  }
}

// ---------------- gram via MFMA: A = 0.01 I + zT zT^T (M=N=512, K=2048) -----
__global__ __launch_bounds__(256) void gram_mfma_k(
    const unsigned short* __restrict__ ZT, float* __restrict__ Am)
{
  __shared__ unsigned short lA[4096];
  __shared__ unsigned short lB[4096];
  const int t = threadIdx.x;
  const int l = t & 63, w = t >> 6;
  int bx = blockIdx.x, by = blockIdx.y;
  xcd_swz(bx, by);
  const int r0 = by << 7, c0 = bx << 7;
  const int K = 2048;
  const int srow = (w << 4) + (l >> 2);
  const int scol = (l & 3) << 3;
  const unsigned short* gA = ZT + (size_t)(r0 + srow) * K + scol;
  const unsigned short* gB = ZT + (size_t)(c0 + srow) * K + scol;
  unsigned short* dA = lA + (w << 9);
  unsigned short* dB = lB + (w << 9);
  const size_t q1 = (size_t)64 * K;
  f32x4 acc[4][4] = {};
  const int wm = (w >> 1) << 6, wn = (w & 1) << 6;
  const int fr = l & 15;
  const int fk = (l >> 4) << 3;
  for (int k0 = 0; k0 < K; k0 += 32) {
    load_lds16(dA,        gA + k0);
    load_lds16(dA + 2048, gA + k0 + q1);
    load_lds16(dB,        gB + k0);
    load_lds16(dB + 2048, gB + k0 + q1);
    asm volatile("s_waitcnt vmcnt(0)" ::: "memory");
    __syncthreads();
    bf16x8 av[4], bv[4];
#pragma unroll
    for (int mi = 0; mi < 4; ++mi)
      av[mi] = *(const bf16x8*)(lA + ((wm + (mi << 4) + fr) << 5) + fk);
#pragma unroll
    for (int ni = 0; ni < 4; ++ni)
      bv[ni] = *(const bf16x8*)(lB + ((wn + (ni << 4) + fr) << 5) + fk);
#pragma unroll
    for (int mi = 0; mi < 4; ++mi)
#pragma unroll
      for (int ni = 0; ni < 4; ++ni)
        acc[mi][ni] = __builtin_amdgcn_mfma_f32_16x16x32_bf16(av[mi], bv[ni], acc[mi][ni], 0, 0, 0);
    __syncthreads();
  }
#pragma unroll
  for (int mi = 0; mi < 4; ++mi) {
    const int row = r0 + wm + (mi << 4) + ((l >> 4) << 2);
#pragma unroll
    for (int ni = 0; ni < 4; ++ni) {
      const int col = c0 + wn + (ni << 4) + (l & 15);
#pragma unroll
      for (int r = 0; r < 4; ++r) {
        float v = acc[mi][ni][r];
        if (row + r == col) v += 0.01f;
        Am[(size_t)(row + r) * 512 + col] = v;
      }
    }
  }
}

// ---------------- bf16 transpose: zb[2048][512] -> zbT[512][2048] -----------
__global__ __launch_bounds__(256) void tr_k(const unsigned short* __restrict__ in,
                                            unsigned short* __restrict__ out)
{
  __shared__ unsigned short tile[64][68];
  const int t = threadIdx.x;
  const int c0 = blockIdx.x << 6;  // i-range
  const int r0 = blockIdx.y << 6;  // b-range
  const int tr = t >> 4, tc = (t & 15) << 2;
#pragma unroll
  for (int p = 0; p < 4; ++p) {
    int r = (p << 4) + tr;
    ushort4 v = *(const ushort4*)&in[(size_t)(r0 + r) * 512 + c0 + tc];
    *(ushort4*)&tile[r][tc] = v;
  }
  __syncthreads();
#pragma unroll
  for (int p = 0; p < 4; ++p) {
    int oc = (p << 4) + tr;
    ushort4 v;
    v.x = tile[tc + 0][oc]; v.y = tile[tc + 1][oc];
    v.z = tile[tc + 2][oc]; v.w = tile[tc + 3][oc];
    *(ushort4*)&out[(size_t)(c0 + oc) * 2048 + r0 + tc] = v;
  }
}

// ---------------- z = mu + eps * exp(0.5*logvar) ----------------------------
__global__ __launch_bounds__(256) void z_k(const float* __restrict__ mu,
    const float* __restrict__ lv, const float* __restrict__ eps,
    float* __restrict__ z, unsigned short* __restrict__ zb)
{
  int i = blockIdx.x * 256 + threadIdx.x;
  float4 m = ((const float4*)mu)[i];
  float4 v = ((const float4*)lv)[i];
  float4 e = ((const float4*)eps)[i];
  float4 r;
  r.x = m.x + e.x * expf(0.5f * v.x);
  r.y = m.y + e.y * expf(0.5f * v.y);
  r.z = m.z + e.z * expf(0.5f * v.z);
  r.w = m.w + e.w * expf(0.5f * v.w);
  ((float4*)z)[i] = r;
  ushort4 o; o.x = f2b(r.x); o.y = f2b(r.y); o.z = f2b(r.z); o.w = f2b(r.w);
  ((ushort4*)zb)[i] = o;
}

// ---------------- RT init: RT = 0.01 * Wout^T -------------------------------
__global__ __launch_bounds__(256) void rhs_init_k(const float* __restrict__ Wout,
                                                  float* __restrict__ RT)
{
  int idx = blockIdx.x * 256 + threadIdx.x;
  if (idx < 5120) {
    int i = idx / 10, c = idx - i * 10;
    RT[idx] = 0.01f * Wout[c * 512 + i];
  }
}

// ---------------- RT += z^T label (split over b, atomics) -------------------
__global__ __launch_bounds__(256) void rhs_part_k(const float* __restrict__ z,
    const float* __restrict__ label, float* __restrict__ RT)
{
  __shared__ float zt[64 * 65];
  __shared__ float lb[640];
  const int t = threadIdx.x;
  const int i0 = blockIdx.x << 6;
  const int bb0 = blockIdx.y << 8;  // 256 b-rows per block
  const int w = t >> 6, il = t & 63;
  float a0 = 0.f, a1 = 0.f, a2 = 0.f;
  for (int b0 = bb0; b0 < bb0 + 256; b0 += 64) {
    __syncthreads();
    for (int idx = t; idx < 4096; idx += 256)
      zt[(idx >> 6) * 65 + (idx & 63)] = z[(size_t)(b0 + (idx >> 6)) * 512 + i0 + (idx & 63)];
    for (int idx = t; idx < 640; idx += 256) lb[idx] = label[b0 * 10 + idx];
    __syncthreads();
    for (int bb = 0; bb < 64; ++bb) {
      float zv = zt[bb * 65 + il];
      a0 += zv * lb[bb * 10 + w];
      a1 += zv * lb[bb * 10 + w + 4];
      if (w < 2) a2 += zv * lb[bb * 10 + w + 8];
    }
  }
  int i = i0 + il;
  atomicAdd(&RT[i * 10 + w], a0);
  atomicAdd(&RT[i * 10 + w + 4], a1);
  if (w < 2) atomicAdd(&RT[i * 10 + w + 8], a2);
}

// ---------------- zero the Gershgorin scalar --------------------------------
__global__ void zero_k(unsigned* __restrict__ g) { g[0] = 0u; }

// ---------------- g = max_i sum_j |A[i][j]| (>= lambda_max) -----------------
__global__ __launch_bounds__(256) void gersh_k(const float* __restrict__ A,
                                               unsigned* __restrict__ g)
{
  const int w = threadIdx.x >> 6, l = threadIdx.x & 63;
  const int row = blockIdx.x * 4 + w;
  const float* ar = A + (size_t)row * 512;
  float s = 0.f;
  for (int j = l; j < 512; j += 64) s += fabsf(ar[j]);
#pragma unroll
  for (int o = 32; o; o >>= 1) s += __shfl_xor(s, o, 64);
  if (l == 0) atomicMax(g, __builtin_bit_cast(unsigned, s));
}

// ---------------- Y0 = (1/g) * I --------------------------------------------
__global__ __launch_bounds__(256) void ns_init_k(const unsigned* __restrict__ g,
                                                 float* __restrict__ Y)
{
  const float alpha = 1.0f / __builtin_bit_cast(float, g[0]);
  int i = blockIdx.x * 256 + threadIdx.x;
  int base = i * 4;
  int row = base >> 9, col = base & 511;
  float4 v = {0.f, 0.f, 0.f, 0.f};
  int d = row - col;
  if (d >= 0 && d < 4) ((float*)&v)[d] = alpha;
  ((float4*)Y)[i] = v;
}

// ---------------- fp32 GEMM 512^3: D = A*B (TWOI: D = 2I - A*B) -------------
template<int TWOI>
__global__ __launch_bounds__(256) void nsgemm_k(const float* __restrict__ A,
    const float* __restrict__ Bm, float* __restrict__ D)
{
  __shared__ float sAT[64 * 34];
  __shared__ float sB[64 * 34];
  const int t = threadIdx.x;
  const int i0 = blockIdx.y << 5, j0 = blockIdx.x << 5;
  const int ti = t >> 4, tj = t & 15;
  float acc00 = 0.f, acc01 = 0.f, acc10 = 0.f, acc11 = 0.f;
  for (int k0 = 0; k0 < 512; k0 += 64) {
    __syncthreads();
    for (int idx = t; idx < 2048; idx += 256) {
      int r = idx >> 6, c = idx & 63;
      sAT[c * 34 + r] = A[(size_t)(i0 + r) * 512 + k0 + c];
      int rb = idx >> 5, cb = idx & 31;
      sB[rb * 34 + cb] = Bm[(size_t)(k0 + rb) * 512 + j0 + cb];
    }
    __syncthreads();
#pragma unroll 8
    for (int kk = 0; kk < 64; ++kk) {
      float2 av = *(const float2*)&sAT[kk * 34 + ti * 2];
      float2 bv = *(const float2*)&sB[kk * 34 + tj * 2];
      acc00 += av.x * bv.x; acc01 += av.x * bv.y;
      acc10 += av.y * bv.x; acc11 += av.y * bv.y;
    }
  }
  const int gi0 = i0 + ti * 2, gj0 = j0 + tj * 2;
  float2 r0 = {acc00, acc01}, r1 = {acc10, acc11};
  if (TWOI) {
    r0.x = (gi0 == gj0 ? 2.f : 0.f) - r0.x;
    r0.y = (gi0 == gj0 + 1 ? 2.f : 0.f) - r0.y;
    r1.x = (gi0 + 1 == gj0 ? 2.f : 0.f) - r1.x;
    r1.y = (gi0 + 1 == gj0 + 1 ? 2.f : 0.f) - r1.y;
  }
  *(float2*)&D[(size_t)gi0 * 512 + gj0] = r0;
  *(float2*)&D[(size_t)(gi0 + 1) * 512 + gj0] = r1;
}

// ---------------- X = Y @ RT (train) or Wout^T (eval) -----------------------
__global__ __launch_bounds__(256) void xform_k(const float* __restrict__ Y,
    const float* __restrict__ RT, const float* __restrict__ Wout,
    const int* __restrict__ mode, float* __restrict__ X)
{
  __shared__ float yt[64 * 65];
  __shared__ float rt[640];
  const int t = threadIdx.x;
  const int i0 = blockIdx.x << 6;
  const int w = t >> 6, il = t & 63;
  float a0 = 0.f, a1 = 0.f, a2 = 0.f;
  for (int j0 = 0; j0 < 512; j0 += 64) {
    __syncthreads();
    for (int idx = t; idx < 4096; idx += 256)
      yt[(idx >> 6) * 65 + (idx & 63)] = Y[(size_t)(i0 + (idx >> 6)) * 512 + j0 + (idx & 63)];
    for (int idx = t; idx < 640; idx += 256) rt[idx] = RT[j0 * 10 + idx];
    __syncthreads();
    for (int jj = 0; jj < 64; ++jj) {
      float yv = yt[il * 65 + jj];
      a0 += yv * rt[jj * 10 + w];
      a1 += yv * rt[jj * 10 + w + 4];
      if (w < 2) a2 += yv * rt[jj * 10 + w + 8];
    }
  }
  const int i = i0 + il;
  const bool train = (*mode == 1);
  X[i * 10 + w]     = train ? a0 : Wout[w * 512 + i];
  X[i * 10 + w + 4] = train ? a1 : Wout[(w + 4) * 512 + i];
  if (w < 2) X[i * 10 + w + 8] = train ? a2 : Wout[(w + 8) * 512 + i];
}

// ---------------- prediction = z @ X ----------------------------------------
__global__ __launch_bounds__(256) void pred_k(const float* __restrict__ z,
    const float* __restrict__ X, float* __restrict__ pred)
{
  __shared__ float xs[5120];
  __shared__ float zs[64 * 65];
  __shared__ float part[2560];
  const int t = threadIdx.x;
  const int b0 = blockIdx.x << 6;
  for (int idx = t; idx < 5120; idx += 256) xs[idx] = X[idx];
  const int rl = t & 63, q = t >> 6;
  float pa[10] = {};
  for (int i0 = 0; i0 < 512; i0 += 64) {
    __syncthreads();
    for (int idx = t; idx < 4096; idx += 256)
      zs[(idx >> 6) * 65 + (idx & 63)] = z[(size_t)(b0 + (idx >> 6)) * 512 + i0 + (idx & 63)];
    __syncthreads();
    for (int iq = 0; iq < 16; ++iq) {
      int ii = (q << 4) + iq;
      float zv = zs[rl * 65 + ii];
#pragma unroll
      for (int c = 0; c < 10; ++c) pa[c] += zv * xs[(i0 + ii) * 10 + c];
    }
  }
  __syncthreads();
#pragma unroll
  for (int c = 0; c < 10; ++c) part[(rl * 4 + q) * 10 + c] = pa[c];
  __syncthreads();
  for (int idx = t; idx < 640; idx += 256) {
    int r = idx / 10, c = idx - r * 10;
    float s = part[(r * 4 + 0) * 10 + c] + part[(r * 4 + 1) * 10 + c] +
              part[(r * 4 + 2) * 10 + c] + part[(r * 4 + 3) * 10 + c];
    pred[(size_t)(b0 + r) * 10 + c] = s;
  }
}

// ============================================================================
extern "C" void kernel_launch(void* const* d_in, const int* in_sizes, int n_in,
                              void* d_out, int out_size, void* d_ws, size_t ws_size,
                              hipStream_t stream)
{
  const float* data  = (const float*)d_in[0];
  const float* label = (const float*)d_in[1];
  const float* eps   = (const float*)d_in[2];
  const float* W_e1  = (const float*)d_in[3];
  const float* b_e1  = (const float*)d_in[4];
  const float* W_e2  = (const float*)d_in[5];
  const float* b_e2  = (const float*)d_in[6];
  const float* W_mu  = (const float*)d_in[7];
  const float* b_mu  = (const float*)d_in[8];
  const float* W_lv  = (const float*)d_in[9];
  const float* b_lv  = (const float*)d_in[10];
  const float* W_d1  = (const float*)d_in[11];
  const float* b_d1  = (const float*)d_in[12];
  const float* W_d2  = (const float*)d_in[13];
  const float* b_d2  = (const float*)d_in[14];
  const float* W_out = (const float*)d_in[15];
  const int*   mode  = (const int*)d_in[17];

  float* out    = (float*)d_out;
  float* o_enc  = out;
  float* o_mu   = out + 1048576;
  float* o_lv   = out + 2097152;
  float* o_z    = out + 3145728;
  float* o_dec  = out + 4194304;
  float* o_pred = out + 12582912;

  char* ws = (char*)d_ws;
  const size_t MB = 1u << 20;
  unsigned short* bfD   = (unsigned short*)(ws + 0 * MB);   // 16 MB (reused)
  unsigned short* bfWe1 = (unsigned short*)(ws + 16 * MB);  // 16 MB (reused)
  unsigned short* h1b   = (unsigned short*)(ws + 32 * MB);  // 8 MB
  unsigned short* bfWe2 = (unsigned short*)(ws + 40 * MB);  // 2 MB
  unsigned short* encb  = (unsigned short*)(ws + 42 * MB);  // 2 MB
  unsigned short* bfWmu = (unsigned short*)(ws + 44 * MB);
  unsigned short* bfWlv = (unsigned short*)(ws + 44 * MB + 512 * 1024);
  unsigned short* zb    = (unsigned short*)(ws + 45 * MB);  // 2 MB
  unsigned short* bfWd1 = (unsigned short*)(ws + 47 * MB);  // 2 MB
  unsigned short* bfWd2 = bfD;
  unsigned short* d1b   = bfWe1;
  float* Amat = (float*)(ws + 49 * MB);           // 1 MB
  float* RTm  = (float*)(ws + 51 * MB);           // 20 KB
  float* Xm   = (float*)(ws + 51 * MB + 65536);   // 20 KB
  unsigned short* zbT = (unsigned short*)(ws + 52 * MB);  // 2 MB
  // NS buffers alias bfD region (dead after GEMM5):
  float* Ya = (float*)(ws + 0 * MB);
  float* Yb = (float*)(ws + 1 * MB);
  float* Sm = (float*)(ws + 2 * MB);
  unsigned* gmax = (unsigned*)(ws + 3 * MB);

  // encoder
  f2bf_k<<<8192, 256, 0, stream>>>(data, bfD);
  f2bf_k<<<8192, 256, 0, stream>>>(W_e1, bfWe1);
  gemm_nt<1,0,1><<<dim3(16,16), 256, 0, stream>>>(bfD, bfWe1, b_e1, nullptr, h1b, 2048, 4096);
  f2bf_k<<<1024, 256, 0, stream>>>(W_e2, bfWe2);
  gemm_nt<1,1,1><<<dim3(4,16), 256, 0, stream>>>(h1b, bfWe2, b_e2, o_enc, encb, 512, 2048);
  // mu / logvar / z
  f2bf_k<<<256, 256, 0, stream>>>(W_mu, bfWmu);
  f2bf_k<<<256, 256, 0, stream>>>(W_lv, bfWlv);
  gemm_nt<0,1,0><<<dim3(4,16), 256, 0, stream>>>(encb, bfWmu, b_mu, o_mu, nullptr, 512, 512);
  gemm_nt<0,1,0><<<dim3(4,16), 256, 0, stream>>>(encb, bfWlv, b_lv, o_lv, nullptr, 512, 512);
  z_k<<<1024, 256, 0, stream>>>(o_mu, o_lv, eps, o_z, zb);
  // decoder
  f2bf_k<<<1024, 256, 0, stream>>>(W_d1, bfWd1);
  gemm_nt<1,0,1><<<dim3(16,16), 256, 0, stream>>>(zb, bfWd1, b_d1, nullptr, d1b, 2048, 512);
  f2bf_k<<<8192, 256, 0, stream>>>(W_d2, bfWd2);
  gemm_nt<0,1,0><<<dim3(32,16), 256, 0, stream>>>(d1b, bfWd2, b_d2, o_dec, nullptr, 4096, 2048);
  // gram: zbT = zb^T, A = 0.01 I + zbT zbT^T (MFMA)
  tr_k<<<dim3(8, 32), 256, 0, stream>>>(zb, zbT);
  gram_mfma_k<<<dim3(4, 4), 256, 0, stream>>>(zbT, Amat);
  // RHS
  rhs_init_k<<<20, 256, 0, stream>>>(W_out, RTm);
  rhs_part_k<<<dim3(8, 8), 256, 0, stream>>>(o_z, label, RTm);
  // Newton-Schulz inverse
  zero_k<<<1, 1, 0, stream>>>(gmax);
  gersh_k<<<128, 256, 0, stream>>>(Amat, gmax);
  ns_init_k<<<256, 256, 0, stream>>>(gmax, Ya);
  float* Yc = Ya;
  for (int it = 0; it < 10; ++it) {
    nsgemm_k<1><<<dim3(16,16), 256, 0, stream>>>(Amat, Yc, Sm);
    float* Yn = (Yc == Ya) ? Yb : Ya;
    nsgemm_k<0><<<dim3(16,16), 256, 0, stream>>>(Yc, Sm, Yn);
    Yc = Yn;
  }
  // X = Y * RT; prediction = z @ X
  xform_k<<<8, 256, 0, stream>>>(Yc, RTm, W_out, mode, Xm);
  pred_k<<<32, 256, 0, stream>>>(o_z, Xm, o_pred);
}

// Round 4
// 849.196 us; speedup vs baseline: 2.0142x; 1.2900x over previous
//
#include <hip/hip_runtime.h>
#include <hip/hip_bf16.h>
#include <cstdint>
#include <cstddef>

// B=2048, D=4096, H=2048, L=512, C=10, RLS_INIT=100
// RLS scan == solve A W^T = R^T, A = 0.01 I + z^T z (shared across classes),
// R = 0.01 W_out + label^T z; prediction = z A^{-1} R^T.
// A SPD -> Newton-Schulz, 7 iters, alpha = 2/(1.125 g + 0.01) (residual ~3e-3,
// X error linear in residual -> plenty).
// Round 4: gram+rhs fused via augmented [z | label] MFMA gram; BN=64 GEMM tiles
// for 2+ blocks/CU; mu/lv fused; NS 10->7.

#define DEV __device__ __forceinline__

typedef __attribute__((ext_vector_type(8))) short bf16x8;
typedef __attribute__((ext_vector_type(4))) float f32x4;

DEV unsigned short f2b(float f) {  // fp32 -> bf16 RNE
  unsigned u = __builtin_bit_cast(unsigned, f);
  u += 0x7FFFu + ((u >> 16) & 1u);
  return (unsigned short)(u >> 16);
}

DEV void load_lds16(void* l, const void* g) {  // async global->LDS, 16B/lane
  __builtin_amdgcn_global_load_lds(
      (const __attribute__((address_space(1))) unsigned int*)g,
      (__attribute__((address_space(3))) unsigned int*)l, 16, 0, 0);
}

// XCD-aware bijective block swizzle (requires nwg%8==0) [T1]
DEV void xcd_swz(int& bx, int& by) {
  int gx = gridDim.x, nwg = gx * gridDim.y;
  int bid = by * gx + bx;
  int swz = (bid & 7) * (nwg >> 3) + (bid >> 3);
  bx = swz % gx; by = swz / gx;
}

// ---------------- fp32 -> bf16 convert --------------------------------------
__global__ __launch_bounds__(256) void f2bf_k(const float* __restrict__ in,
                                              unsigned short* __restrict__ out) {
  int i = blockIdx.x * 256 + threadIdx.x;
  float4 v = ((const float4*)in)[i];
  ushort4 o;
  o.x = f2b(v.x); o.y = f2b(v.y); o.z = f2b(v.z); o.w = f2b(v.w);
  ((ushort4*)out)[i] = o;
}

// ---------------- bf16 MFMA GEMM: C = act(A[M,K] @ B[N,K]^T + bias) ---------
// BM=128 fixed; BN in {64,128}. 4 waves. BN=128: wave 64x64 (4x4 frags);
// BN=64: wave 64x32 (4x2 frags). SPLIT: cols>=512 go to Cf2/bias2 (stride 512).
template<int RELU, int WF32, int WBF16, int BN, int SPLIT>
__global__ __launch_bounds__(256) void gemm_nt(
    const unsigned short* __restrict__ A, const unsigned short* __restrict__ Bm,
    const float* __restrict__ bias, const float* __restrict__ bias2,
    float* __restrict__ Cf, float* __restrict__ Cf2,
    unsigned short* __restrict__ Cb, int N, int K)
{
  constexpr int NF = BN / 32;            // n-frags per wave (4 or 2)
  __shared__ unsigned short lA[4096];
  __shared__ unsigned short lB[BN * 32];
  const int t = threadIdx.x;
  const int l = t & 63, w = t >> 6;
  int bx = blockIdx.x, by = blockIdx.y;
  xcd_swz(bx, by);
  const int r0 = by << 7, c0 = bx * BN;
  const int srow = (w << 4) + (l >> 2);
  const int scol = (l & 3) << 3;
  const unsigned short* gA = A + (size_t)(r0 + srow) * K + scol;
  const unsigned short* gB = Bm + (size_t)(c0 + srow) * K + scol;
  unsigned short* dA = lA + (w << 9);
  unsigned short* dB = lB + (w << 9);
  const size_t q1 = (size_t)64 * K;
  f32x4 acc[4][NF];
#pragma unroll
  for (int a = 0; a < 4; ++a)
#pragma unroll
    for (int b = 0; b < NF; ++b) acc[a][b] = (f32x4){0.f, 0.f, 0.f, 0.f};
  const int wm = (w >> 1) << 6;
  const int wn = (BN == 128) ? ((w & 1) << 6) : ((w & 1) << 5);
  const int fr = l & 15;
  const int fk = (l >> 4) << 3;
  for (int k0 = 0; k0 < K; k0 += 32) {
    load_lds16(dA,        gA + k0);
    load_lds16(dA + 2048, gA + k0 + q1);
    load_lds16(dB,        gB + k0);
    if (BN == 128) load_lds16(dB + 2048, gB + k0 + q1);
    asm volatile("s_waitcnt vmcnt(0)" ::: "memory");
    __syncthreads();
    bf16x8 av[4], bv[NF];
#pragma unroll
    for (int mi = 0; mi < 4; ++mi)
      av[mi] = *(const bf16x8*)(lA + ((wm + (mi << 4) + fr) << 5) + fk);
#pragma unroll
    for (int ni = 0; ni < NF; ++ni)
      bv[ni] = *(const bf16x8*)(lB + ((wn + (ni << 4) + fr) << 5) + fk);
#pragma unroll
    for (int mi = 0; mi < 4; ++mi)
#pragma unroll
      for (int ni = 0; ni < NF; ++ni)
        acc[mi][ni] = __builtin_amdgcn_mfma_f32_16x16x32_bf16(av[mi], bv[ni], acc[mi][ni], 0, 0, 0);
    __syncthreads();
  }
  // epilogue: C/D layout col=lane&15, row=(lane>>4)*4+reg  [m89-verified]
#pragma unroll
  for (int mi = 0; mi < 4; ++mi) {
    const int row = r0 + wm + (mi << 4) + ((l >> 4) << 2);
#pragma unroll
    for (int ni = 0; ni < NF; ++ni) {
      const int col = c0 + wn + (ni << 4) + (l & 15);
      float bvs;
      if (SPLIT) bvs = (col < 512) ? bias[col] : bias2[col - 512];
      else       bvs = bias[col];
#pragma unroll
      for (int r = 0; r < 4; ++r) {
        float v = acc[mi][ni][r] + bvs;
        if (RELU) v = v > 0.f ? v : 0.f;
        if (SPLIT) {
          if (col < 512) Cf[(size_t)(row + r) * 512 + col] = v;
          else           Cf2[(size_t)(row + r) * 512 + col - 512] = v;
        } else {
          const size_t idx = (size_t)(row + r) * N + col;
          if (WF32) Cf[idx] = v;
          if (WBF16) Cb[idx] = f2b(v);
        }
      }
    }
  }
}

// ---------------- gram+rhs via MFMA on augmented ZL^T [640][2048] -----------
// P = ZL @ ZL^T; cols<512 -> Am (+0.01 diag); cols 512..521 -> RT + 0.01 Wout^T
__global__ __launch_bounds__(256) void gram_rhs_k(
    const unsigned short* __restrict__ ZT, const float* __restrict__ Wout,
    float* __restrict__ Am, float* __restrict__ RT)
{
  __shared__ unsigned short lA[4096];
  __shared__ unsigned short lB[4096];
  const int t = threadIdx.x;
  const int l = t & 63, w = t >> 6;
  const int bx = blockIdx.x, by = blockIdx.y;  // (5, 4) grid, no swizzle
  const int r0 = by << 7, c0 = bx << 7;
  const int K = 2048;
  const int srow = (w << 4) + (l >> 2);
  const int scol = (l & 3) << 3;
  const unsigned short* gA = ZT + (size_t)(r0 + srow) * K + scol;
  const unsigned short* gB = ZT + (size_t)(c0 + srow) * K + scol;
  unsigned short* dA = lA + (w << 9);
  unsigned short* dB = lB + (w << 9);
  const size_t q1 = (size_t)64 * K;
  f32x4 acc[4][4] = {};
  const int wm = (w >> 1) << 6, wn = (w & 1) << 6;
  const int fr = l & 15;
  const int fk = (l >> 4) << 3;
  for (int k0 = 0; k0 < K; k0 += 32) {
    load_lds16(dA,        gA + k0);
    load_lds16(dA + 2048, gA + k0 + q1);
    load_lds16(dB,        gB + k0);
    load_lds16(dB + 2048, gB + k0 + q1);
    asm volatile("s_waitcnt vmcnt(0)" ::: "memory");
    __syncthreads();
    bf16x8 av[4], bv[4];
#pragma unroll
    for (int mi = 0; mi < 4; ++mi)
      av[mi] = *(const bf16x8*)(lA + ((wm + (mi << 4) + fr) << 5) + fk);
#pragma unroll
    for (int ni = 0; ni < 4; ++ni)
      bv[ni] = *(const bf16x8*)(lB + ((wn + (ni << 4) + fr) << 5) + fk);
#pragma unroll
    for (int mi = 0; mi < 4; ++mi)
#pragma unroll
      for (int ni = 0; ni < 4; ++ni)
        acc[mi][ni] = __builtin_amdgcn_mfma_f32_16x16x32_bf16(av[mi], bv[ni], acc[mi][ni], 0, 0, 0);
    __syncthreads();
  }
#pragma unroll
  for (int mi = 0; mi < 4; ++mi) {
    const int row = r0 + wm + (mi << 4) + ((l >> 4) << 2);
#pragma unroll
    for (int ni = 0; ni < 4; ++ni) {
      const int col = c0 + wn + (ni << 4) + (l & 15);
#pragma unroll
      for (int r = 0; r < 4; ++r) {
        float v = acc[mi][ni][r];
        const int rr = row + r;
        if (col < 512) {
          if (rr == col) v += 0.01f;
          Am[(size_t)rr * 512 + col] = v;
        } else if (col < 522) {
          const int c = col - 512;
          RT[rr * 10 + c] = v + 0.01f * Wout[c * 512 + rr];
        }
      }
    }
  }
}

// ---------------- bf16 transpose: zb[2048][512] -> zlT[0:512][2048] ---------
__global__ __launch_bounds__(256) void tr_k(const unsigned short* __restrict__ in,
                                            unsigned short* __restrict__ out)
{
  __shared__ unsigned short tile[64][68];
  const int t = threadIdx.x;
  const int c0 = blockIdx.x << 6;  // i-range
  const int r0 = blockIdx.y << 6;  // b-range
  const int tr = t >> 4, tc = (t & 15) << 2;
#pragma unroll
  for (int p = 0; p < 4; ++p) {
    int r = (p << 4) + tr;
    ushort4 v = *(const ushort4*)&in[(size_t)(r0 + r) * 512 + c0 + tc];
    *(ushort4*)&tile[r][tc] = v;
  }
  __syncthreads();
#pragma unroll
  for (int p = 0; p < 4; ++p) {
    int oc = (p << 4) + tr;
    ushort4 v;
    v.x = tile[tc + 0][oc]; v.y = tile[tc + 1][oc];
    v.z = tile[tc + 2][oc]; v.w = tile[tc + 3][oc];
    *(ushort4*)&out[(size_t)(c0 + oc) * 2048 + r0 + tc] = v;
  }
}

// ---------------- labelT: zlT rows 512..639 = [label^T bf16; zeros] ---------
__global__ __launch_bounds__(256) void labelT_k(const float* __restrict__ label,
                                                unsigned short* __restrict__ out)
{
  int idx = blockIdx.x * 256 + threadIdx.x;  // 128*2048 elems
  int r = idx >> 11, b = idx & 2047;
  unsigned short v = 0;
  if (r < 10) v = f2b(label[b * 10 + r]);
  out[(size_t)(512 + r) * 2048 + b] = v;
}

// ---------------- z = mu + eps * exp(0.5*logvar) ----------------------------
__global__ __launch_bounds__(256) void z_k(const float* __restrict__ mu,
    const float* __restrict__ lv, const float* __restrict__ eps,
    float* __restrict__ z, unsigned short* __restrict__ zb)
{
  int i = blockIdx.x * 256 + threadIdx.x;
  float4 m = ((const float4*)mu)[i];
  float4 v = ((const float4*)lv)[i];
  float4 e = ((const float4*)eps)[i];
  float4 r;
  r.x = m.x + e.x * expf(0.5f * v.x);
  r.y = m.y + e.y * expf(0.5f * v.y);
  r.z = m.z + e.z * expf(0.5f * v.z);
  r.w = m.w + e.w * expf(0.5f * v.w);
  ((float4*)z)[i] = r;
  ushort4 o; o.x = f2b(r.x); o.y = f2b(r.y); o.z = f2b(r.z); o.w = f2b(r.w);
  ((ushort4*)zb)[i] = o;
}

// ---------------- zero the Gershgorin scalar --------------------------------
__global__ void zero_k(unsigned* __restrict__ g) { g[0] = 0u; }

// ---------------- g = max_i sum_j |A[i][j]| (>= lambda_max) -----------------
__global__ __launch_bounds__(256) void gersh_k(const float* __restrict__ A,
                                               unsigned* __restrict__ g)
{
  const int w = threadIdx.x >> 6, l = threadIdx.x & 63;
  const int row = blockIdx.x * 4 + w;
  const float* ar = A + (size_t)row * 512;
  float s = 0.f;
  for (int j = l; j < 512; j += 64) s += fabsf(ar[j]);
#pragma unroll
  for (int o = 32; o; o >>= 1) s += __shfl_xor(s, o, 64);
  if (l == 0) atomicMax(g, __builtin_bit_cast(unsigned, s));
}

// ---------------- Y0 = alpha * I, alpha = 2/(1.125 g + 0.01) ----------------
__global__ __launch_bounds__(256) void ns_init_k(const unsigned* __restrict__ g,
                                                 float* __restrict__ Y)
{
  const float gv = __builtin_bit_cast(float, g[0]);
  const float alpha = 2.0f / (1.125f * gv + 0.01f);
  int i = blockIdx.x * 256 + threadIdx.x;
  int base = i * 4;
  int row = base >> 9, col = base & 511;
  float4 v = {0.f, 0.f, 0.f, 0.f};
  int d = row - col;
  if (d >= 0 && d < 4) ((float*)&v)[d] = alpha;
  ((float4*)Y)[i] = v;
}

// ---------------- fp32 GEMM 512^3: D = A*B (TWOI: D = 2I - A*B) -------------
template<int TWOI>
__global__ __launch_bounds__(256) void nsgemm_k(const float* __restrict__ A,
    const float* __restrict__ Bm, float* __restrict__ D)
{
  __shared__ float sAT[64 * 34];
  __shared__ float sB[64 * 34];
  const int t = threadIdx.x;
  const int i0 = blockIdx.y << 5, j0 = blockIdx.x << 5;
  const int ti = t >> 4, tj = t & 15;
  float acc00 = 0.f, acc01 = 0.f, acc10 = 0.f, acc11 = 0.f;
  for (int k0 = 0; k0 < 512; k0 += 64) {
    __syncthreads();
    for (int idx = t; idx < 2048; idx += 256) {
      int r = idx >> 6, c = idx & 63;
      sAT[c * 34 + r] = A[(size_t)(i0 + r) * 512 + k0 + c];
      int rb = idx >> 5, cb = idx & 31;
      sB[rb * 34 + cb] = Bm[(size_t)(k0 + rb) * 512 + j0 + cb];
    }
    __syncthreads();
#pragma unroll 8
    for (int kk = 0; kk < 64; ++kk) {
      float2 av = *(const float2*)&sAT[kk * 34 + ti * 2];
      float2 bv = *(const float2*)&sB[kk * 34 + tj * 2];
      acc00 += av.x * bv.x; acc01 += av.x * bv.y;
      acc10 += av.y * bv.x; acc11 += av.y * bv.y;
    }
  }
  const int gi0 = i0 + ti * 2, gj0 = j0 + tj * 2;
  float2 r0 = {acc00, acc01}, r1 = {acc10, acc11};
  if (TWOI) {
    r0.x = (gi0 == gj0 ? 2.f : 0.f) - r0.x;
    r0.y = (gi0 == gj0 + 1 ? 2.f : 0.f) - r0.y;
    r1.x = (gi0 + 1 == gj0 ? 2.f : 0.f) - r1.x;
    r1.y = (gi0 + 1 == gj0 + 1 ? 2.f : 0.f) - r1.y;
  }
  *(float2*)&D[(size_t)gi0 * 512 + gj0] = r0;
  *(float2*)&D[(size_t)(gi0 + 1) * 512 + gj0] = r1;
}

// ---------------- X = Y @ RT (train) or Wout^T (eval) -----------------------
__global__ __launch_bounds__(256) void xform_k(const float* __restrict__ Y,
    const float* __restrict__ RT, const float* __restrict__ Wout,
    const int* __restrict__ mode, float* __restrict__ X)
{
  __shared__ float yt[64 * 65];
  __shared__ float rt[640];
  const int t = threadIdx.x;
  const int i0 = blockIdx.x << 6;
  const int w = t >> 6, il = t & 63;
  float a0 = 0.f, a1 = 0.f, a2 = 0.f;
  for (int j0 = 0; j0 < 512; j0 += 64) {
    __syncthreads();
    for (int idx = t; idx < 4096; idx += 256)
      yt[(idx >> 6) * 65 + (idx & 63)] = Y[(size_t)(i0 + (idx >> 6)) * 512 + j0 + (idx & 63)];
    for (int idx = t; idx < 640; idx += 256) rt[idx] = RT[j0 * 10 + idx];
    __syncthreads();
    for (int jj = 0; jj < 64; ++jj) {
      float yv = yt[il * 65 + jj];
      a0 += yv * rt[jj * 10 + w];
      a1 += yv * rt[jj * 10 + w + 4];
      if (w < 2) a2 += yv * rt[jj * 10 + w + 8];
    }
  }
  const int i = i0 + il;
  const bool train = (*mode == 1);
  X[i * 10 + w]     = train ? a0 : Wout[w * 512 + i];
  X[i * 10 + w + 4] = train ? a1 : Wout[(w + 4) * 512 + i];
  if (w < 2) X[i * 10 + w + 8] = train ? a2 : Wout[(w + 8) * 512 + i];
}

// ---------------- prediction = z @ X ----------------------------------------
__global__ __launch_bounds__(256) void pred_k(const float* __restrict__ z,
    const float* __restrict__ X, float* __restrict__ pred)
{
  __shared__ float xs[5120];
  __shared__ float zs[64 * 65];
  __shared__ float part[2560];
  const int t = threadIdx.x;
  const int b0 = blockIdx.x << 6;
  for (int idx = t; idx < 5120; idx += 256) xs[idx] = X[idx];
  const int rl = t & 63, q = t >> 6;
  float pa[10] = {};
  for (int i0 = 0; i0 < 512; i0 += 64) {
    __syncthreads();
    for (int idx = t; idx < 4096; idx += 256)
      zs[(idx >> 6) * 65 + (idx & 63)] = z[(size_t)(b0 + (idx >> 6)) * 512 + i0 + (idx & 63)];
    __syncthreads();
    for (int iq = 0; iq < 16; ++iq) {
      int ii = (q << 4) + iq;
      float zv = zs[rl * 65 + ii];
#pragma unroll
      for (int c = 0; c < 10; ++c) pa[c] += zv * xs[(i0 + ii) * 10 + c];
    }
  }
  __syncthreads();
#pragma unroll
  for (int c = 0; c < 10; ++c) part[(rl * 4 + q) * 10 + c] = pa[c];
  __syncthreads();
  for (int idx = t; idx < 640; idx += 256) {
    int r = idx / 10, c = idx - r * 10;
    float s = part[(r * 4 + 0) * 10 + c] + part[(r * 4 + 1) * 10 + c] +
              part[(r * 4 + 2) * 10 + c] + part[(r * 4 + 3) * 10 + c];
    pred[(size_t)(b0 + r) * 10 + c] = s;
  }
}

// ============================================================================
extern "C" void kernel_launch(void* const* d_in, const int* in_sizes, int n_in,
                              void* d_out, int out_size, void* d_ws, size_t ws_size,
                              hipStream_t stream)
{
  const float* data  = (const float*)d_in[0];
  const float* label = (const float*)d_in[1];
  const float* eps   = (const float*)d_in[2];
  const float* W_e1  = (const float*)d_in[3];
  const float* b_e1  = (const float*)d_in[4];
  const float* W_e2  = (const float*)d_in[5];
  const float* b_e2  = (const float*)d_in[6];
  const float* W_mu  = (const float*)d_in[7];
  const float* b_mu  = (const float*)d_in[8];
  const float* W_lv  = (const float*)d_in[9];
  const float* b_lv  = (const float*)d_in[10];
  const float* W_d1  = (const float*)d_in[11];
  const float* b_d1  = (const float*)d_in[12];
  const float* W_d2  = (const float*)d_in[13];
  const float* b_d2  = (const float*)d_in[14];
  const float* W_out = (const float*)d_in[15];
  const int*   mode  = (const int*)d_in[17];

  float* out    = (float*)d_out;
  float* o_enc  = out;
  float* o_mu   = out + 1048576;
  float* o_lv   = out + 2097152;
  float* o_z    = out + 3145728;
  float* o_dec  = out + 4194304;
  float* o_pred = out + 12582912;

  char* ws = (char*)d_ws;
  const size_t MB = 1u << 20;
  unsigned short* bfD   = (unsigned short*)(ws + 0 * MB);   // 16 MB (reused)
  unsigned short* bfWe1 = (unsigned short*)(ws + 16 * MB);  // 16 MB (reused)
  unsigned short* h1b   = (unsigned short*)(ws + 32 * MB);  // 8 MB
  unsigned short* bfWe2 = (unsigned short*)(ws + 40 * MB);  // 2 MB
  unsigned short* encb  = (unsigned short*)(ws + 42 * MB);  // 2 MB
  unsigned short* bfWmu = (unsigned short*)(ws + 44 * MB);            // 512 KB
  unsigned short* bfWlv = (unsigned short*)(ws + 44 * MB + 512 * 1024); // contiguous!
  unsigned short* zb    = (unsigned short*)(ws + 45 * MB);  // 2 MB
  unsigned short* bfWd1 = (unsigned short*)(ws + 47 * MB);  // 2 MB
  unsigned short* bfWd2 = bfD;
  unsigned short* d1b   = bfWe1;
  float* Amat = (float*)(ws + 49 * MB);           // 1 MB
  float* RTm  = (float*)(ws + 51 * MB);           // 20 KB
  float* Xm   = (float*)(ws + 51 * MB + 65536);   // 20 KB
  unsigned short* zlT = (unsigned short*)(ws + 52 * MB);  // [640][2048] bf16 = 2.5 MB
  // NS buffers alias bfD region (dead after GEMM5):
  float* Ya = (float*)(ws + 0 * MB);
  float* Yb = (float*)(ws + 1 * MB);
  float* Sm = (float*)(ws + 2 * MB);
  unsigned* gmax = (unsigned*)(ws + 3 * MB);

  // encoder
  f2bf_k<<<8192, 256, 0, stream>>>(data, bfD);
  f2bf_k<<<8192, 256, 0, stream>>>(W_e1, bfWe1);
  gemm_nt<1,0,1,64,0><<<dim3(32,16), 256, 0, stream>>>(bfD, bfWe1, b_e1, nullptr, nullptr, nullptr, h1b, 2048, 4096);
  f2bf_k<<<1024, 256, 0, stream>>>(W_e2, bfWe2);
  gemm_nt<1,1,1,64,0><<<dim3(8,16), 256, 0, stream>>>(h1b, bfWe2, b_e2, nullptr, o_enc, nullptr, encb, 512, 2048);
  // mu / logvar (fused: bfWmu||bfWlv contiguous = [1024][512]) / z
  f2bf_k<<<256, 256, 0, stream>>>(W_mu, bfWmu);
  f2bf_k<<<256, 256, 0, stream>>>(W_lv, bfWlv);
  gemm_nt<0,1,0,64,1><<<dim3(16,16), 256, 0, stream>>>(encb, bfWmu, b_mu, b_lv, o_mu, o_lv, nullptr, 512, 512);
  z_k<<<1024, 256, 0, stream>>>(o_mu, o_lv, eps, o_z, zb);
  // decoder
  f2bf_k<<<1024, 256, 0, stream>>>(W_d1, bfWd1);
  gemm_nt<1,0,1,64,0><<<dim3(32,16), 256, 0, stream>>>(zb, bfWd1, b_d1, nullptr, nullptr, nullptr, d1b, 2048, 512);
  f2bf_k<<<8192, 256, 0, stream>>>(W_d2, bfWd2);
  gemm_nt<0,1,0,128,0><<<dim3(32,16), 256, 0, stream>>>(d1b, bfWd2, b_d2, nullptr, o_dec, nullptr, nullptr, 4096, 2048);
  // gram+rhs: zlT = [zb^T ; label^T ; 0], P = zlT zlT^T -> Am, RTm
  tr_k<<<dim3(8, 32), 256, 0, stream>>>(zb, zlT);
  labelT_k<<<1024, 256, 0, stream>>>(label, zlT);
  gram_rhs_k<<<dim3(5, 4), 256, 0, stream>>>(zlT, W_out, Amat, RTm);
  // Newton-Schulz inverse (7 iters)
  zero_k<<<1, 1, 0, stream>>>(gmax);
  gersh_k<<<128, 256, 0, stream>>>(Amat, gmax);
  ns_init_k<<<256, 256, 0, stream>>>(gmax, Ya);
  float* Yc = Ya;
  for (int it = 0; it < 7; ++it) {
    nsgemm_k<1><<<dim3(16,16), 256, 0, stream>>>(Amat, Yc, Sm);
    float* Yn = (Yc == Ya) ? Yb : Ya;
    nsgemm_k<0><<<dim3(16,16), 256, 0, stream>>>(Yc, Sm, Yn);
    Yc = Yn;
  }
  // X = Y * RT; prediction = z @ X
  xform_k<<<8, 256, 0, stream>>>(Yc, RTm, W_out, mode, Xm);
  pred_k<<<32, 256, 0, stream>>>(o_z, Xm, o_pred);
}